// Round 11
// baseline (885.089 us; speedup 1.0000x reference)
//
#include <hip/hip_runtime.h>
#include <vector>
#include <algorithm>
#include <cstdint>
#include <cstring>
#include <cmath>

// ===================== host-side JAX threefry replication =====================
static inline uint32_t tf_rotl(uint32_t x, int r) { return (x << r) | (x >> (32 - r)); }

static void tf2x32(uint32_t k0, uint32_t k1, uint32_t x0, uint32_t x1,
                   uint32_t* o0, uint32_t* o1) {
  uint32_t ks2 = k0 ^ k1 ^ 0x1BD11BDAu;
  uint32_t v0 = x0 + k0, v1 = x1 + k1;
  static const int R0[4] = {13, 15, 26, 6}, R1[4] = {17, 29, 16, 24};
#define RND4(R) do { for (int i_ = 0; i_ < 4; ++i_) { v0 += v1; v1 = tf_rotl(v1, R[i_]); v1 ^= v0; } } while (0)
  RND4(R0); v0 += k1;  v1 += ks2 + 1u;
  RND4(R1); v0 += ks2; v1 += k0 + 2u;
  RND4(R0); v0 += k0;  v1 += k1 + 3u;
  RND4(R1); v0 += k1;  v1 += ks2 + 4u;
  RND4(R0); v0 += ks2; v1 += k0 + 5u;
#undef RND4
  *o0 = v0; *o1 = v1;
}

static void jax_permutation(uint32_t seed, int n, int rounds, int* x) {
  uint32_t k0 = 0u, k1 = seed;
  for (int i = 0; i < n; ++i) x[i] = i;
  std::vector<uint32_t> bits(n);
  std::vector<int> ord(n), xn(n);
  for (int r = 0; r < rounds; ++r) {
    uint32_t nk0, nk1, sk0, sk1;
    tf2x32(k0, k1, 0u, 0u, &nk0, &nk1);
    tf2x32(k0, k1, 0u, 1u, &sk0, &sk1);
    for (int i = 0; i < n; ++i) {
      uint32_t h, l;
      tf2x32(sk0, sk1, 0u, (uint32_t)i, &h, &l);
      bits[i] = h ^ l;
    }
    for (int i = 0; i < n; ++i) ord[i] = i;
    std::stable_sort(ord.begin(), ord.end(),
                     [&](int a, int b) { return bits[a] < bits[b]; });
    for (int i = 0; i < n; ++i) xn[i] = x[ord[i]];
    memcpy(x, xn.data(), (size_t)n * sizeof(int));
    k0 = nk0; k1 = nk1;
  }
}

// ===================== device kernels =====================
#define NEI 20

__device__ __forceinline__ float san(float v) {
  v = (v != v) ? 0.0f : v;
  return fmaxf(-1e4f, fminf(v, 1e4f));
}

// fused setup: blocks 0..63 sanitize vertices -> AoS + SoA + sq;
// blocks 64..87 normalize the 5 direction matrices.
__global__ void k_setup(const float* __restrict__ vin, float* __restrict__ outA,
                        float* __restrict__ xs, float* __restrict__ ys,
                        float* __restrict__ zs, float* __restrict__ sqs, int nverts,
                        const float* __restrict__ d0, const float* __restrict__ d1,
                        const float* __restrict__ d2, const float* __restrict__ d3,
                        const float* __restrict__ d4,
                        float* __restrict__ s0, float* __restrict__ s1,
                        float* __restrict__ s2, float* __restrict__ s3,
                        float* __restrict__ s4) {
  int blk = blockIdx.x;
  if (blk < 64) {
    int i = blk * 256 + threadIdx.x;
    if (i >= nverts) return;
    float x = san(vin[3 * i]), y = san(vin[3 * i + 1]), z = san(vin[3 * i + 2]);
    outA[3 * i] = x; outA[3 * i + 1] = y; outA[3 * i + 2] = z;
    xs[i] = x; ys[i] = y; zs[i] = z;
    sqs[i] = x * x + y * y + z * z;
    return;
  }
  int t = (blk - 64) * 256 + threadIdx.x;
  const float* d; float* s; int E, e;
  if (t < 128)       { d = d0; s = s0; E = 128;  e = t; }
  else if (t < 384)  { d = d1; s = s1; E = 256;  e = t - 128; }
  else if (t < 896)  { d = d2; s = s2; E = 512;  e = t - 384; }
  else if (t < 1920) { d = d3; s = s3; E = 1024; e = t - 896; }
  else if (t < 6016) { d = d4; s = s4; E = 4096; e = t - 1920; }
  else return;
  float a = san(d[e]);
  float b = san(d[E + e]);
  float c = san(d[2 * E + e]);
  float nrm = sqrtf(a * a + b * b + c * c);
  float m = fmaxf(nrm, 1e-12f);
  s[e] = a / m; s[E + e] = b / m; s[2 * E + e] = c / m;
}

// total-order map for fp32 bits: monotone u32 for any float (handles negatives)
__device__ __forceinline__ unsigned fmap(float f) {
  unsigned u = __float_as_uint(f);
  return u ^ ((u & 0x80000000u) ? 0xFFFFFFFFu : 0x80000000u);
}

// --- 64-lane u32 min, broadcast to all lanes: 6 DPP (VALU pipe) + 1 shfl ---
__device__ __forceinline__ unsigned dpp_min_bcast1(unsigned a) {
  unsigned t;
  t = (unsigned)__builtin_amdgcn_update_dpp((int)a, (int)a, 0xB1, 0xF, 0xF, true);
  a = t < a ? t : a;
  t = (unsigned)__builtin_amdgcn_update_dpp((int)a, (int)a, 0x4E, 0xF, 0xF, true);
  a = t < a ? t : a;
  t = (unsigned)__builtin_amdgcn_update_dpp((int)a, (int)a, 0x141, 0xF, 0xF, true);
  a = t < a ? t : a;
  t = (unsigned)__builtin_amdgcn_update_dpp((int)a, (int)a, 0x140, 0xF, 0xF, true);
  a = t < a ? t : a;
  t = (unsigned)__builtin_amdgcn_update_dpp((int)a, (int)a, 0x142, 0xA, 0xF, false);
  a = t < a ? t : a;
  t = (unsigned)__builtin_amdgcn_update_dpp((int)a, (int)a, 0x143, 0xC, 0xF, false);
  a = t < a ? t : a;
  return (unsigned)__shfl((int)a, 63);
}

__device__ __forceinline__ void dpp_min_bcast2(unsigned& a, unsigned& b) {
  unsigned t0, t1;
#define STEP_DPP(ctrl, rm, bc)                                                           \
  t0 = (unsigned)__builtin_amdgcn_update_dpp((int)a, (int)a, ctrl, rm, 0xF, bc);         \
  t1 = (unsigned)__builtin_amdgcn_update_dpp((int)b, (int)b, ctrl, rm, 0xF, bc);         \
  a = t0 < a ? t0 : a; b = t1 < b ? t1 : b;
  STEP_DPP(0xB1, 0xF, true)
  STEP_DPP(0x4E, 0xF, true)
  STEP_DPP(0x141, 0xF, true)
  STEP_DPP(0x140, 0xF, true)
  STEP_DPP(0x142, 0xA, false)
  STEP_DPP(0x143, 0xC, false)
#undef STEP_DPP
  a = (unsigned)__shfl((int)a, 63);
  b = (unsigned)__shfl((int)b, 63);
}

// sorted top-3 insert (exec-masked nested ifs; cheap when inserts are rare)
__device__ __forceinline__ void q_ins(unsigned long long k, unsigned long long& a0,
                                      unsigned long long& a1, unsigned long long& a2) {
  if (k < a2) {
    if (k < a1) {
      a2 = a1;
      if (k < a0) { a1 = a0; a0 = k; } else { a1 = k; }
    } else {
      a2 = k;
    }
  }
}

// rescan one parity class of this lane's candidates for min key > bound
template <int VCAND>
__device__ __forceinline__ unsigned long long refill_scan(
    const float* __restrict__ xs, const float* __restrict__ ys,
    const float* __restrict__ zs, const float* __restrict__ sqs,
    int base, int lane, float xi, float yi, float zi, float sqi,
    unsigned long long bound, int parity) {
  unsigned long long nm = ~0ULL;
  for (int c = parity; c < VCAND; c += 2) {
    int j = c * 64 + lane;
    float xj = xs[base + j], yj = ys[base + j], zj = zs[base + j];
    float sqj = sqs[base + j];
    float dot = xi * xj + yi * yj + zi * zj;
    float dd = (sqi + sqj) - 2.0f * dot;
    unsigned long long k = (((unsigned long long)fmap(dd)) << 32) | (unsigned)j;
    if (k > bound && k < nm) nm = k;
  }
  return nm;
}

// KNN v9: two queries per wave; per query TWO independent lane-local top-3
// queues (even/odd candidate parity) => 2x ILP on the init-scan insert chain.
// Per round: u64 min of the two heads, u32 DPP min over the mapped dist word,
// ballot tie-break by index (exact). Pop from the queue that held the winner;
// refill that parity with filter > popped key (exact; keys unique).
// Selection order identical to lax.top_k lexicographic (dist, j) order.
template <int VCAND>
__global__ __launch_bounds__(256, 8) void k_knn9(const float* __restrict__ xs,
                                                 const float* __restrict__ ys,
                                                 const float* __restrict__ zs,
                                                 const float* __restrict__ sqs,
                                                 int* __restrict__ nidx, int V) {
  const int wid = threadIdx.x >> 6;
  const int lane = threadIdx.x & 63;
  const int row0 = blockIdx.x * 8 + wid * 2;
  const int b = row0 / V;
  const int base = b * V;
  const int i0 = row0 % V;

  float xi[2], yi[2], zi[2], sqi[2];
#pragma unroll
  for (int t = 0; t < 2; ++t) {
    xi[t] = xs[base + i0 + t]; yi[t] = ys[base + i0 + t]; zi[t] = zs[base + i0 + t];
    sqi[t] = sqs[base + i0 + t];
  }

  unsigned long long qa0[2] = {~0ULL, ~0ULL}, qa1[2] = {~0ULL, ~0ULL}, qa2[2] = {~0ULL, ~0ULL};
  unsigned long long qb0[2] = {~0ULL, ~0ULL}, qb1[2] = {~0ULL, ~0ULL}, qb2[2] = {~0ULL, ~0ULL};
#pragma unroll 8
  for (int c = 0; c < VCAND; ++c) {
    int j = c * 64 + lane;
    float xj = xs[base + j], yj = ys[base + j], zj = zs[base + j];
    float sqj = sqs[base + j];
#pragma unroll
    for (int t = 0; t < 2; ++t) {
      float dot = xi[t] * xj + yi[t] * yj + zi[t] * zj;
      float dd = (sqi[t] + sqj) - 2.0f * dot;
      unsigned long long k = (((unsigned long long)fmap(dd)) << 32) | (unsigned)j;
      if ((c & 1) == 0) q_ins(k, qa0[t], qa1[t], qa2[t]);
      else              q_ins(k, qb0[t], qb1[t], qb2[t]);
    }
  }

  for (int r = 0; r < 21; ++r) {
    unsigned long long hm0 = qa0[0] < qb0[0] ? qa0[0] : qb0[0];
    unsigned long long hm1 = qa0[1] < qb0[1] ? qa0[1] : qb0[1];
    unsigned h0 = (unsigned)(hm0 >> 32);
    unsigned h1 = (unsigned)(hm1 >> 32);
    unsigned m0 = h0, m1 = h1;
    dpp_min_bcast2(m0, m1);
    unsigned long long mk0 = __ballot(h0 == m0);
    unsigned long long mk1 = __ballot(h1 == m1);
    bool win0, win1;
    if (__popcll(mk0) > 1) {  // rare: dist-bit tie across lanes -> index min
      unsigned jj = (h0 == m0) ? (unsigned)hm0 : 0xFFFFFFFFu;
      unsigned jm = dpp_min_bcast1(jj);
      win0 = (h0 == m0) && ((unsigned)hm0 == jm);
    } else {
      win0 = (h0 == m0);
    }
    if (__popcll(mk1) > 1) {
      unsigned jj = (h1 == m1) ? (unsigned)hm1 : 0xFFFFFFFFu;
      unsigned jm = dpp_min_bcast1(jj);
      win1 = (h1 == m1) && ((unsigned)hm1 == jm);
    } else {
      win1 = (h1 == m1);
    }
    if (win0) {
      if (r > 0) nidx[(size_t)row0 * NEI + (r - 1)] = (int)(unsigned)hm0;
      if (hm0 == qa0[0]) {
        qa0[0] = qa1[0]; qa1[0] = qa2[0]; qa2[0] = ~0ULL;
        if (qa0[0] == ~0ULL)
          qa0[0] = refill_scan<VCAND>(xs, ys, zs, sqs, base, lane, xi[0], yi[0], zi[0], sqi[0], hm0, 0);
      } else {
        qb0[0] = qb1[0]; qb1[0] = qb2[0]; qb2[0] = ~0ULL;
        if (qb0[0] == ~0ULL)
          qb0[0] = refill_scan<VCAND>(xs, ys, zs, sqs, base, lane, xi[0], yi[0], zi[0], sqi[0], hm0, 1);
      }
    }
    if (win1) {
      if (r > 0) nidx[(size_t)(row0 + 1) * NEI + (r - 1)] = (int)(unsigned)hm1;
      if (hm1 == qa0[1]) {
        qa0[1] = qa1[1]; qa1[1] = qa2[1]; qa2[1] = ~0ULL;
        if (qa0[1] == ~0ULL)
          qa0[1] = refill_scan<VCAND>(xs, ys, zs, sqs, base, lane, xi[1], yi[1], zi[1], sqi[1], hm1, 0);
      } else {
        qb0[1] = qb1[1]; qb1[1] = qb2[1]; qb2[1] = ~0ULL;
        if (qb0[1] == ~0ULL)
          qb0[1] = refill_scan<VCAND>(xs, ys, zs, sqs, base, lane, xi[1], yi[1], zi[1], sqi[1], hm1, 1);
      }
    }
  }
}

// conv_surface: C=32, E=128. One block (128 thr) per (b,v).
__global__ __launch_bounds__(128) void k_conv_surface(const float* __restrict__ verts,
                                                      const int* __restrict__ nidx,
                                                      const float* __restrict__ sd,
                                                      float* __restrict__ fm, int V) {
  int row = blockIdx.x;
  int b = row / V, v = row % V;
  const float* vb = verts + (size_t)b * V * 3;
  __shared__ float nd[60];
  __shared__ float mcol[128];
  int tid = threadIdx.x;
  if (tid < NEI) {
    int j = nidx[(size_t)row * NEI + tid];
    float dx = vb[3 * j] - vb[3 * v];
    float dy = vb[3 * j + 1] - vb[3 * v + 1];
    float dz = vb[3 * j + 2] - vb[3 * v + 2];
    float nrm = sqrtf(dx * dx + dy * dy + dz * dz);
    float m = fmaxf(nrm, 1e-12f);
    nd[tid * 3] = dx / m; nd[tid * 3 + 1] = dy / m; nd[tid * 3 + 2] = dz / m;
  }
  __syncthreads();
  {
    int e = tid;
    float s0 = sd[e], s1 = sd[128 + e], s2 = sd[256 + e];
    float me = 0.0f;
#pragma unroll
    for (int n = 0; n < NEI; ++n) {
      float th = nd[3 * n] * s0 + nd[3 * n + 1] * s1 + nd[3 * n + 2] * s2;
      th = fmaxf(th, 0.0f);
      me = fmaxf(me, th);
    }
    mcol[e] = me;
  }
  __syncthreads();
  if (tid < 32) {
    float o = mcol[tid] + mcol[32 + tid] + mcol[64 + tid] + mcol[96 + tid];
    o = fmaxf(o, 0.0f);
    fm[(size_t)row * 32 + tid] = o;
  }
}

// fp32 tiled GEMM 64x64x16 (guarded; used for layer1): C = A*W + bias
__global__ __launch_bounds__(256) void k_gemm_bias(const float* __restrict__ A,
                                                   const float* __restrict__ W,
                                                   const float* __restrict__ bias,
                                                   float* __restrict__ Cm,
                                                   int M, int N, int K) {
  __shared__ float As[16][68];
  __shared__ float Bs[16][68];
  int n0 = blockIdx.x * 64, m0 = blockIdx.y * 64;
  int tx = threadIdx.x & 15, ty = threadIdx.x >> 4;
  float acc[4][4] = {};
  for (int k0 = 0; k0 < K; k0 += 16) {
    for (int t = threadIdx.x; t < 1024; t += 256) {
      int mm = t >> 4, kk = t & 15;
      int m = m0 + mm;
      As[kk][mm] = (m < M) ? A[(size_t)m * K + (k0 + kk)] : 0.0f;
    }
    for (int t = threadIdx.x; t < 1024; t += 256) {
      int kk = t >> 6, nn = t & 63;
      int n = n0 + nn;
      Bs[kk][nn] = (n < N) ? san(W[(size_t)(k0 + kk) * N + n]) : 0.0f;
    }
    __syncthreads();
#pragma unroll
    for (int kk = 0; kk < 16; ++kk) {
      float4 av = *(const float4*)&As[kk][ty << 2];
      float4 bv = *(const float4*)&Bs[kk][tx << 2];
      float a[4] = {av.x, av.y, av.z, av.w};
      float bb[4] = {bv.x, bv.y, bv.z, bv.w};
#pragma unroll
      for (int i = 0; i < 4; ++i)
#pragma unroll
        for (int j = 0; j < 4; ++j) acc[i][j] += a[i] * bb[j];
    }
    __syncthreads();
  }
  for (int i = 0; i < 4; ++i)
    for (int j = 0; j < 4; ++j) {
      int m = m0 + (ty << 2) + i, n = n0 + (tx << 2) + j;
      if (m < M && n < N) Cm[(size_t)m * N + n] = acc[i][j] + san(bias[n]);
    }
}

// fp32 tiled GEMM 128x128x32, requires M%128==0, N%128==0, K%32==0.
__global__ __launch_bounds__(256) void k_gemm128(const float* __restrict__ A,
                                                 const float* __restrict__ W,
                                                 const float* __restrict__ bias,
                                                 float* __restrict__ Cm,
                                                 int M, int N, int K) {
  __shared__ float As[32][132];
  __shared__ float Bs[32][132];
  const int n0 = blockIdx.x * 128, m0 = blockIdx.y * 128;
  const int tx = threadIdx.x & 15, ty = threadIdx.x >> 4;
  const int bm = ty * 8;
  float acc[8][8] = {};
  float bias_lo[4], bias_hi[4];
#pragma unroll
  for (int j = 0; j < 4; ++j) {
    bias_lo[j] = san(bias[n0 + tx * 4 + j]);
    bias_hi[j] = san(bias[n0 + 64 + tx * 4 + j]);
  }
  for (int k0 = 0; k0 < K; k0 += 32) {
#pragma unroll
    for (int r = 0; r < 4; ++r) {
      int t = r * 256 + threadIdx.x;
      int mm = t >> 3, kk = (t & 7) * 4;
      float4 v = *(const float4*)&A[(size_t)(m0 + mm) * K + k0 + kk];
      As[kk + 0][mm] = v.x; As[kk + 1][mm] = v.y; As[kk + 2][mm] = v.z; As[kk + 3][mm] = v.w;
    }
#pragma unroll
    for (int r = 0; r < 4; ++r) {
      int t = r * 256 + threadIdx.x;
      int kk = t >> 5, nn = (t & 31) * 4;
      float4 v = *(const float4*)&W[(size_t)(k0 + kk) * N + n0 + nn];
      *(float4*)&Bs[kk][nn] = v;
    }
    __syncthreads();
#pragma unroll
    for (int kk = 0; kk < 32; ++kk) {
      float4 a0 = *(const float4*)&As[kk][bm];
      float4 a1 = *(const float4*)&As[kk][bm + 4];
      float4 b0 = *(const float4*)&Bs[kk][tx * 4];
      float4 b1 = *(const float4*)&Bs[kk][64 + tx * 4];
      float a[8] = {a0.x, a0.y, a0.z, a0.w, a1.x, a1.y, a1.z, a1.w};
      float bb[8] = {b0.x, b0.y, b0.z, b0.w, b1.x, b1.y, b1.z, b1.w};
#pragma unroll
      for (int i = 0; i < 8; ++i)
#pragma unroll
        for (int j = 0; j < 8; ++j) acc[i][j] += a[i] * bb[j];
    }
    __syncthreads();
  }
#pragma unroll
  for (int i = 0; i < 8; ++i) {
    int m = m0 + bm + i;
    float4 lo = {acc[i][0] + bias_lo[0], acc[i][1] + bias_lo[1],
                 acc[i][2] + bias_lo[2], acc[i][3] + bias_lo[3]};
    float4 hi = {acc[i][4] + bias_hi[0], acc[i][5] + bias_hi[1],
                 acc[i][6] + bias_hi[2], acc[i][7] + bias_hi[3]};
    *(float4*)&Cm[(size_t)m * N + n0 + tx * 4] = lo;
    *(float4*)&Cm[(size_t)m * N + n0 + 64 + tx * 4] = hi;
  }
}

// conv layer: out[c] = f[row][c] + sum_s max_n relu(nd_n . sd_e) * f[j_n][C+e]
__global__ __launch_bounds__(256) void k_conv_layer(const float* __restrict__ f,
                                                    const float* __restrict__ verts,
                                                    const int* __restrict__ nidx,
                                                    const float* __restrict__ sd,
                                                    float* __restrict__ outf,
                                                    int V, int C, int relu_out) {
  int row = blockIdx.x;
  int b = row / V, v = row % V;
  int E = 4 * C;
  extern __shared__ float sm[];
  float* mcol = sm;
  float* nd = sm + E;
  int* jr = (int*)(nd + 60);
  int tid = threadIdx.x;
  const float* vb = verts + (size_t)b * V * 3;
  if (tid < NEI) {
    int j = nidx[(size_t)row * NEI + tid];
    jr[tid] = j;
    float dx = vb[3 * j] - vb[3 * v];
    float dy = vb[3 * j + 1] - vb[3 * v + 1];
    float dz = vb[3 * j + 2] - vb[3 * v + 2];
    float nrm = sqrtf(dx * dx + dy * dy + dz * dz);
    float m = fmaxf(nrm, 1e-12f);
    nd[tid * 3] = dx / m; nd[tid * 3 + 1] = dy / m; nd[tid * 3 + 2] = dz / m;
  }
  __syncthreads();
  size_t fb = (size_t)b * V;
  int fivec = 5 * C;
  for (int e = tid; e < E; e += blockDim.x) {
    float s0 = sd[e], s1 = sd[E + e], s2 = sd[2 * E + e];
    float me = -INFINITY;
#pragma unroll
    for (int n = 0; n < NEI; ++n) {
      float th = nd[3 * n] * s0 + nd[3 * n + 1] * s1 + nd[3 * n + 2] * s2;
      th = fmaxf(th, 0.0f);
      float fv = f[(fb + jr[n]) * (size_t)fivec + C + e];
      me = fmaxf(me, th * fv);
    }
    mcol[e] = me;
  }
  __syncthreads();
  for (int c = tid; c < C; c += blockDim.x) {
    float o = f[(size_t)row * fivec + c] + mcol[c] + mcol[C + c] + mcol[2 * C + c] + mcol[3 * C + c];
    if (relu_out) o = fmaxf(o, 0.0f);
    outf[(size_t)row * C + c] = o;
  }
}

// transpose (B, V, C) -> (B, C, V), 32x32 LDS tiles, coalesced both sides
__global__ __launch_bounds__(256) void k_transpose_vc(const float* __restrict__ in,
                                                      float* __restrict__ out,
                                                      int V, int C) {
  __shared__ float tile[32][33];
  int b = blockIdx.z;
  int c0 = blockIdx.x * 32, v0 = blockIdx.y * 32;
  int tx = threadIdx.x & 31, ty4 = threadIdx.x >> 5;
#pragma unroll
  for (int j = 0; j < 4; ++j) {
    int v = v0 + ty4 * 4 + j;
    tile[ty4 * 4 + j][tx] = in[((size_t)b * V + v) * C + c0 + tx];
  }
  __syncthreads();
#pragma unroll
  for (int j = 0; j < 4; ++j) {
    int c = c0 + ty4 * 4 + j;
    out[((size_t)b * C + c) * V + v0 + tx] = tile[tx][ty4 * 4 + j];
  }
}

// fused pool (max over neighbors at selected rows) + pooled-vertex gather
__global__ void k_pool_sel(const float* __restrict__ fm, const int* __restrict__ nidx,
                           const int* __restrict__ sel, float* __restrict__ outp,
                           const float* __restrict__ vinA, float* __restrict__ voutA,
                           float* __restrict__ xs, float* __restrict__ ys,
                           float* __restrict__ zs, float* __restrict__ sqs,
                           int Vin, int Vout, int C) {
  int t = blockIdx.x * blockDim.x + threadIdx.x;
  if (t < 4 * Vout) {
    int p = t % Vout;
    int b = t / Vout;
    int src = b * Vin + sel[p];
    float x = vinA[3 * src], y = vinA[3 * src + 1], z = vinA[3 * src + 2];
    int dst = b * Vout + p;
    voutA[3 * dst] = x; voutA[3 * dst + 1] = y; voutA[3 * dst + 2] = z;
    xs[dst] = x; ys[dst] = y; zs[dst] = z;
    sqs[dst] = x * x + y * y + z * z;
  }
  int total = 4 * Vout * C;
  if (t >= total) return;
  int c = t % C;
  int p = (t / C) % Vout;
  int b = t / (C * Vout);
  int sv = sel[p];
  const int* ir = nidx + ((size_t)b * Vin + sv) * NEI;
  float m = -INFINITY;
#pragma unroll
  for (int n = 0; n < NEI; ++n)
    m = fmaxf(m, fm[((size_t)b * Vin + ir[n]) * C + c]);
  outp[((size_t)b * Vout + p) * C + c] = m;
}

// ===================== launch =====================
extern "C" void kernel_launch(void* const* d_in, const int* in_sizes, int n_in,
                              void* d_out, int out_size, void* d_ws, size_t ws_size,
                              hipStream_t stream) {
  (void)in_sizes; (void)n_in; (void)out_size; (void)ws_size;
  const int B = 4, V1 = 4096, V2 = 1024, V3 = 256;

  const float* vin   = (const float*)d_in[0];
  const float* dirs0 = (const float*)d_in[1];
  const float* W1 = (const float*)d_in[2];
  const float* b1 = (const float*)d_in[3];
  const float* D1 = (const float*)d_in[4];
  const float* W2 = (const float*)d_in[5];
  const float* b2 = (const float*)d_in[6];
  const float* D2 = (const float*)d_in[7];
  const float* W3 = (const float*)d_in[8];
  const float* b3 = (const float*)d_in[9];
  const float* D3 = (const float*)d_in[10];
  const float* W4 = (const float*)d_in[11];
  const float* b4 = (const float*)d_in[12];
  const float* D4 = (const float*)d_in[13];
  float* out = (float*)d_out;

  char* ws = (char*)d_ws;
  size_t off = 0;
  auto alloc = [&](size_t bytes) -> char* {
    char* p = ws + off;
    off = (off + bytes + 255) & ~(size_t)255;
    return p;
  };
  int* sel1 = (int*)alloc((size_t)V2 * 4);
  int* sel2 = (int*)alloc((size_t)V3 * 4);
  float* verts1 = (float*)alloc((size_t)B * V1 * 3 * 4);
  float* verts2 = (float*)alloc((size_t)B * V2 * 3 * 4);
  float* verts3 = (float*)alloc((size_t)B * V3 * 3 * 4);
  float* xs1 = (float*)alloc((size_t)B * V1 * 4);
  float* ys1 = (float*)alloc((size_t)B * V1 * 4);
  float* zs1 = (float*)alloc((size_t)B * V1 * 4);
  float* sq1 = (float*)alloc((size_t)B * V1 * 4);
  float* xs2 = (float*)alloc((size_t)B * V2 * 4);
  float* ys2 = (float*)alloc((size_t)B * V2 * 4);
  float* zs2 = (float*)alloc((size_t)B * V2 * 4);
  float* sq2 = (float*)alloc((size_t)B * V2 * 4);
  float* xs3 = (float*)alloc((size_t)B * V3 * 4);
  float* ys3 = (float*)alloc((size_t)B * V3 * 4);
  float* zs3 = (float*)alloc((size_t)B * V3 * 4);
  float* sq3 = (float*)alloc((size_t)B * V3 * 4);
  int* idx1 = (int*)alloc((size_t)B * V1 * NEI * 4);
  int* idx2 = (int*)alloc((size_t)B * V2 * NEI * 4);
  int* idx3 = (int*)alloc((size_t)B * V3 * NEI * 4);
  float* sd0 = (float*)alloc(3 * 128 * 4);
  float* sd1 = (float*)alloc(3 * 256 * 4);
  float* sd2 = (float*)alloc(3 * 512 * 4);
  float* sd3 = (float*)alloc(3 * 1024 * 4);
  float* sd4 = (float*)alloc(3 * 4096 * 4);
  float* bufA = (float*)alloc((size_t)B * V1 * 32 * 4);
  float* bufB = (float*)alloc((size_t)B * V1 * 64 * 4);
  float* bufC = (float*)alloc((size_t)B * V2 * 64 * 4);
  float* fbuf = (float*)alloc((size_t)B * V1 * 320 * 4);
  float* fm0 = bufA, *fm2 = bufA;
  float* fm1 = bufB, *fm3 = bufB;
  float* fm1p = bufC, *fm3p = bufC;
  float* conv4out = bufB;

  static int perm1[4096];
  static int perm2[1024];
  static int selh[1280];
  jax_permutation(42u, 4096, 2, perm1);
  jax_permutation(43u, 1024, 1, perm2);
  memcpy(selh, perm1, 1024 * sizeof(int));
  memcpy(selh + 1024, perm2, 256 * sizeof(int));
  hipMemcpyAsync(sel1, selh, 1024 * sizeof(int), hipMemcpyHostToDevice, stream);
  hipMemcpyAsync(sel2, selh + 1024, 256 * sizeof(int), hipMemcpyHostToDevice, stream);

  // fused sanitize + dirs normalize
  k_setup<<<88, 256, 0, stream>>>(vin, verts1, xs1, ys1, zs1, sq1, B * V1,
                                  dirs0, D1, D2, D3, D4, sd0, sd1, sd2, sd3, sd4);
  // knn level 1 (VCAND = 64), 2 queries/wave, 8 queries/block
  k_knn9<64><<<B * V1 / 8, 256, 0, stream>>>(xs1, ys1, zs1, sq1, idx1, V1);
  k_conv_surface<<<B * V1, 128, 0, stream>>>(verts1, idx1, sd0, fm0, V1);
  // layer1 (N=320 not /128 -> 64-tile)
  k_gemm_bias<<<dim3(5, 256), 256, 0, stream>>>(fm0, W1, b1, fbuf, B * V1, 320, 32);
  k_conv_layer<<<B * V1, 256, (4 * 64 + 80) * 4, stream>>>(fbuf, verts1, idx1, sd1, fm1, V1, 64, 1);
  // pool1 (fused pool + vertex gather)
  {
    int total = B * V2 * 64;
    k_pool_sel<<<(total + 255) / 256, 256, 0, stream>>>(fm1, idx1, sel1, fm1p,
                                                        verts1, verts2, xs2, ys2, zs2, sq2,
                                                        V1, V2, 64);
  }
  // knn level 2 (VCAND = 16)
  k_knn9<16><<<B * V2 / 8, 256, 0, stream>>>(xs2, ys2, zs2, sq2, idx2, V2);
  // layer2: 4096x640x64
  k_gemm128<<<dim3(640 / 128, 4096 / 128), 256, 0, stream>>>(fm1p, W2, b2, fbuf, B * V2, 640, 64);
  k_conv_layer<<<B * V2, 256, (4 * 128 + 80) * 4, stream>>>(fbuf, verts2, idx2, sd2, fm2, V2, 128, 1);
  // layer3: 4096x1280x128
  k_gemm128<<<dim3(1280 / 128, 4096 / 128), 256, 0, stream>>>(fm2, W3, b3, fbuf, B * V2, 1280, 128);
  k_conv_layer<<<B * V2, 256, (4 * 256 + 80) * 4, stream>>>(fbuf, verts2, idx2, sd3, fm3, V2, 256, 1);
  // pool2 (fused)
  {
    int total = B * V3 * 256;
    k_pool_sel<<<(total + 255) / 256, 256, 0, stream>>>(fm3, idx2, sel2, fm3p,
                                                        verts2, verts3, xs3, ys3, zs3, sq3,
                                                        V2, V3, 256);
  }
  // knn level 3 (VCAND = 4)
  k_knn9<4><<<B * V3 / 8, 256, 0, stream>>>(xs3, ys3, zs3, sq3, idx3, V3);
  // layer4: 1024x5120x256, conv C=1024 row-major, then coalesced transpose
  k_gemm128<<<dim3(5120 / 128, 1024 / 128), 256, 0, stream>>>(fm3p, W4, b4, fbuf, B * V3, 5120, 256);
  k_conv_layer<<<B * V3, 256, (4 * 1024 + 80) * 4, stream>>>(fbuf, verts3, idx3, sd4, conv4out, V3, 1024, 0);
  k_transpose_vc<<<dim3(1024 / 32, 256 / 32, B), 256, 0, stream>>>(conv4out, out, V3, 1024);
}

// Round 12
// 858.081 us; speedup vs baseline: 1.0315x; 1.0315x over previous
//
#include <hip/hip_runtime.h>
#include <vector>
#include <algorithm>
#include <cstdint>
#include <cstring>
#include <cmath>

// ===================== host-side JAX threefry replication =====================
static inline uint32_t tf_rotl(uint32_t x, int r) { return (x << r) | (x >> (32 - r)); }

static void tf2x32(uint32_t k0, uint32_t k1, uint32_t x0, uint32_t x1,
                   uint32_t* o0, uint32_t* o1) {
  uint32_t ks2 = k0 ^ k1 ^ 0x1BD11BDAu;
  uint32_t v0 = x0 + k0, v1 = x1 + k1;
  static const int R0[4] = {13, 15, 26, 6}, R1[4] = {17, 29, 16, 24};
#define RND4(R) do { for (int i_ = 0; i_ < 4; ++i_) { v0 += v1; v1 = tf_rotl(v1, R[i_]); v1 ^= v0; } } while (0)
  RND4(R0); v0 += k1;  v1 += ks2 + 1u;
  RND4(R1); v0 += ks2; v1 += k0 + 2u;
  RND4(R0); v0 += k0;  v1 += k1 + 3u;
  RND4(R1); v0 += k1;  v1 += ks2 + 4u;
  RND4(R0); v0 += ks2; v1 += k0 + 5u;
#undef RND4
  *o0 = v0; *o1 = v1;
}

static void jax_permutation(uint32_t seed, int n, int rounds, int* x) {
  uint32_t k0 = 0u, k1 = seed;
  for (int i = 0; i < n; ++i) x[i] = i;
  std::vector<uint32_t> bits(n);
  std::vector<int> ord(n), xn(n);
  for (int r = 0; r < rounds; ++r) {
    uint32_t nk0, nk1, sk0, sk1;
    tf2x32(k0, k1, 0u, 0u, &nk0, &nk1);
    tf2x32(k0, k1, 0u, 1u, &sk0, &sk1);
    for (int i = 0; i < n; ++i) {
      uint32_t h, l;
      tf2x32(sk0, sk1, 0u, (uint32_t)i, &h, &l);
      bits[i] = h ^ l;
    }
    for (int i = 0; i < n; ++i) ord[i] = i;
    std::stable_sort(ord.begin(), ord.end(),
                     [&](int a, int b) { return bits[a] < bits[b]; });
    for (int i = 0; i < n; ++i) xn[i] = x[ord[i]];
    memcpy(x, xn.data(), (size_t)n * sizeof(int));
    k0 = nk0; k1 = nk1;
  }
}

// ===================== device kernels =====================
#define NEI 20

__device__ __forceinline__ float san(float v) {
  v = (v != v) ? 0.0f : v;
  return fmaxf(-1e4f, fminf(v, 1e4f));
}

// fused setup: blocks 0..63 sanitize vertices -> AoS + SoA + sq;
// blocks 64..87 normalize the 5 direction matrices.
__global__ void k_setup(const float* __restrict__ vin, float* __restrict__ outA,
                        float* __restrict__ xs, float* __restrict__ ys,
                        float* __restrict__ zs, float* __restrict__ sqs, int nverts,
                        const float* __restrict__ d0, const float* __restrict__ d1,
                        const float* __restrict__ d2, const float* __restrict__ d3,
                        const float* __restrict__ d4,
                        float* __restrict__ s0, float* __restrict__ s1,
                        float* __restrict__ s2, float* __restrict__ s3,
                        float* __restrict__ s4) {
  int blk = blockIdx.x;
  if (blk < 64) {
    int i = blk * 256 + threadIdx.x;
    if (i >= nverts) return;
    float x = san(vin[3 * i]), y = san(vin[3 * i + 1]), z = san(vin[3 * i + 2]);
    outA[3 * i] = x; outA[3 * i + 1] = y; outA[3 * i + 2] = z;
    xs[i] = x; ys[i] = y; zs[i] = z;
    sqs[i] = x * x + y * y + z * z;
    return;
  }
  int t = (blk - 64) * 256 + threadIdx.x;
  const float* d; float* s; int E, e;
  if (t < 128)       { d = d0; s = s0; E = 128;  e = t; }
  else if (t < 384)  { d = d1; s = s1; E = 256;  e = t - 128; }
  else if (t < 896)  { d = d2; s = s2; E = 512;  e = t - 384; }
  else if (t < 1920) { d = d3; s = s3; E = 1024; e = t - 896; }
  else if (t < 6016) { d = d4; s = s4; E = 4096; e = t - 1920; }
  else return;
  float a = san(d[e]);
  float b = san(d[E + e]);
  float c = san(d[2 * E + e]);
  float nrm = sqrtf(a * a + b * b + c * c);
  float m = fmaxf(nrm, 1e-12f);
  s[e] = a / m; s[E + e] = b / m; s[2 * E + e] = c / m;
}

// total-order map for fp32 bits: monotone u32 for any float (handles negatives)
__device__ __forceinline__ unsigned fmap(float f) {
  unsigned u = __float_as_uint(f);
  return u ^ ((u & 0x80000000u) ? 0xFFFFFFFFu : 0x80000000u);
}

// --- 64-lane u32 min, broadcast to all lanes: 6 DPP (VALU pipe) + 1 shfl ---
__device__ __forceinline__ unsigned dpp_min_bcast1(unsigned a) {
  unsigned t;
  t = (unsigned)__builtin_amdgcn_update_dpp((int)a, (int)a, 0xB1, 0xF, 0xF, true);
  a = t < a ? t : a;
  t = (unsigned)__builtin_amdgcn_update_dpp((int)a, (int)a, 0x4E, 0xF, 0xF, true);
  a = t < a ? t : a;
  t = (unsigned)__builtin_amdgcn_update_dpp((int)a, (int)a, 0x141, 0xF, 0xF, true);
  a = t < a ? t : a;
  t = (unsigned)__builtin_amdgcn_update_dpp((int)a, (int)a, 0x140, 0xF, 0xF, true);
  a = t < a ? t : a;
  t = (unsigned)__builtin_amdgcn_update_dpp((int)a, (int)a, 0x142, 0xA, 0xF, false);
  a = t < a ? t : a;
  t = (unsigned)__builtin_amdgcn_update_dpp((int)a, (int)a, 0x143, 0xC, 0xF, false);
  a = t < a ? t : a;
  return (unsigned)__shfl((int)a, 63);
}

__device__ __forceinline__ void dpp_min_bcast2(unsigned& a, unsigned& b) {
  unsigned t0, t1;
#define STEP_DPP(ctrl, rm, bc)                                                           \
  t0 = (unsigned)__builtin_amdgcn_update_dpp((int)a, (int)a, ctrl, rm, 0xF, bc);         \
  t1 = (unsigned)__builtin_amdgcn_update_dpp((int)b, (int)b, ctrl, rm, 0xF, bc);         \
  a = t0 < a ? t0 : a; b = t1 < b ? t1 : b;
  STEP_DPP(0xB1, 0xF, true)
  STEP_DPP(0x4E, 0xF, true)
  STEP_DPP(0x141, 0xF, true)
  STEP_DPP(0x140, 0xF, true)
  STEP_DPP(0x142, 0xA, false)
  STEP_DPP(0x143, 0xC, false)
#undef STEP_DPP
  a = (unsigned)__shfl((int)a, 63);
  b = (unsigned)__shfl((int)b, 63);
}

// sorted top-3 insert (exec-masked nested ifs; cheap when inserts are rare)
__device__ __forceinline__ void q_ins(unsigned long long k, unsigned long long& a0,
                                      unsigned long long& a1, unsigned long long& a2) {
  if (k < a2) {
    if (k < a1) {
      a2 = a1;
      if (k < a0) { a1 = a0; a0 = k; } else { a1 = k; }
    } else {
      a2 = k;
    }
  }
}

// rescan one parity class of this lane's candidates for min key > bound
template <int VCAND>
__device__ __forceinline__ unsigned long long refill_scan(
    const float* __restrict__ xs, const float* __restrict__ ys,
    const float* __restrict__ zs, const float* __restrict__ sqs,
    int base, int lane, float xi, float yi, float zi, float sqi,
    unsigned long long bound, int parity) {
  unsigned long long nm = ~0ULL;
  for (int c = parity; c < VCAND; c += 2) {
    int j = c * 64 + lane;
    float xj = xs[base + j], yj = ys[base + j], zj = zs[base + j];
    float sqj = sqs[base + j];
    float dot = xi * xj + yi * yj + zi * zj;
    float dd = (sqi + sqj) - 2.0f * dot;
    unsigned long long k = (((unsigned long long)fmap(dd)) << 32) | (unsigned)j;
    if (k > bound && k < nm) nm = k;
  }
  return nm;
}

// KNN v10: identical algorithm to v9 (dual parity queues per query for insert
// ILP) but __launch_bounds__(256,4): 128-VGPR budget so the 12 u64 queues live
// in registers. R11's (256,8) forced 32 VGPRs -> queues spilled to scratch
// (1.1 GB WRITE_SIZE, 4.7x regression). Measured occupancy was ~4 waves/EU
// anyway, so the relaxed bound costs nothing.
template <int VCAND>
__global__ __launch_bounds__(256, 4) void k_knn10(const float* __restrict__ xs,
                                                  const float* __restrict__ ys,
                                                  const float* __restrict__ zs,
                                                  const float* __restrict__ sqs,
                                                  int* __restrict__ nidx, int V) {
  const int wid = threadIdx.x >> 6;
  const int lane = threadIdx.x & 63;
  const int row0 = blockIdx.x * 8 + wid * 2;
  const int b = row0 / V;
  const int base = b * V;
  const int i0 = row0 % V;

  float xi[2], yi[2], zi[2], sqi[2];
#pragma unroll
  for (int t = 0; t < 2; ++t) {
    xi[t] = xs[base + i0 + t]; yi[t] = ys[base + i0 + t]; zi[t] = zs[base + i0 + t];
    sqi[t] = sqs[base + i0 + t];
  }

  unsigned long long qa0[2] = {~0ULL, ~0ULL}, qa1[2] = {~0ULL, ~0ULL}, qa2[2] = {~0ULL, ~0ULL};
  unsigned long long qb0[2] = {~0ULL, ~0ULL}, qb1[2] = {~0ULL, ~0ULL}, qb2[2] = {~0ULL, ~0ULL};
#pragma unroll 8
  for (int c = 0; c < VCAND; ++c) {
    int j = c * 64 + lane;
    float xj = xs[base + j], yj = ys[base + j], zj = zs[base + j];
    float sqj = sqs[base + j];
#pragma unroll
    for (int t = 0; t < 2; ++t) {
      float dot = xi[t] * xj + yi[t] * yj + zi[t] * zj;
      float dd = (sqi[t] + sqj) - 2.0f * dot;
      unsigned long long k = (((unsigned long long)fmap(dd)) << 32) | (unsigned)j;
      if ((c & 1) == 0) q_ins(k, qa0[t], qa1[t], qa2[t]);
      else              q_ins(k, qb0[t], qb1[t], qb2[t]);
    }
  }

  for (int r = 0; r < 21; ++r) {
    unsigned long long hm0 = qa0[0] < qb0[0] ? qa0[0] : qb0[0];
    unsigned long long hm1 = qa0[1] < qb0[1] ? qa0[1] : qb0[1];
    unsigned h0 = (unsigned)(hm0 >> 32);
    unsigned h1 = (unsigned)(hm1 >> 32);
    unsigned m0 = h0, m1 = h1;
    dpp_min_bcast2(m0, m1);
    unsigned long long mk0 = __ballot(h0 == m0);
    unsigned long long mk1 = __ballot(h1 == m1);
    bool win0, win1;
    if (__popcll(mk0) > 1) {  // rare: dist-bit tie across lanes -> index min
      unsigned jj = (h0 == m0) ? (unsigned)hm0 : 0xFFFFFFFFu;
      unsigned jm = dpp_min_bcast1(jj);
      win0 = (h0 == m0) && ((unsigned)hm0 == jm);
    } else {
      win0 = (h0 == m0);
    }
    if (__popcll(mk1) > 1) {
      unsigned jj = (h1 == m1) ? (unsigned)hm1 : 0xFFFFFFFFu;
      unsigned jm = dpp_min_bcast1(jj);
      win1 = (h1 == m1) && ((unsigned)hm1 == jm);
    } else {
      win1 = (h1 == m1);
    }
    if (win0) {
      if (r > 0) nidx[(size_t)row0 * NEI + (r - 1)] = (int)(unsigned)hm0;
      if (hm0 == qa0[0]) {
        qa0[0] = qa1[0]; qa1[0] = qa2[0]; qa2[0] = ~0ULL;
        if (qa0[0] == ~0ULL)
          qa0[0] = refill_scan<VCAND>(xs, ys, zs, sqs, base, lane, xi[0], yi[0], zi[0], sqi[0], hm0, 0);
      } else {
        qb0[0] = qb1[0]; qb1[0] = qb2[0]; qb2[0] = ~0ULL;
        if (qb0[0] == ~0ULL)
          qb0[0] = refill_scan<VCAND>(xs, ys, zs, sqs, base, lane, xi[0], yi[0], zi[0], sqi[0], hm0, 1);
      }
    }
    if (win1) {
      if (r > 0) nidx[(size_t)(row0 + 1) * NEI + (r - 1)] = (int)(unsigned)hm1;
      if (hm1 == qa0[1]) {
        qa0[1] = qa1[1]; qa1[1] = qa2[1]; qa2[1] = ~0ULL;
        if (qa0[1] == ~0ULL)
          qa0[1] = refill_scan<VCAND>(xs, ys, zs, sqs, base, lane, xi[1], yi[1], zi[1], sqi[1], hm1, 0);
      } else {
        qb0[1] = qb1[1]; qb1[1] = qb2[1]; qb2[1] = ~0ULL;
        if (qb0[1] == ~0ULL)
          qb0[1] = refill_scan<VCAND>(xs, ys, zs, sqs, base, lane, xi[1], yi[1], zi[1], sqi[1], hm1, 1);
      }
    }
  }
}

// conv_surface: C=32, E=128. One block (128 thr) per (b,v).
__global__ __launch_bounds__(128) void k_conv_surface(const float* __restrict__ verts,
                                                      const int* __restrict__ nidx,
                                                      const float* __restrict__ sd,
                                                      float* __restrict__ fm, int V) {
  int row = blockIdx.x;
  int b = row / V, v = row % V;
  const float* vb = verts + (size_t)b * V * 3;
  __shared__ float nd[60];
  __shared__ float mcol[128];
  int tid = threadIdx.x;
  if (tid < NEI) {
    int j = nidx[(size_t)row * NEI + tid];
    float dx = vb[3 * j] - vb[3 * v];
    float dy = vb[3 * j + 1] - vb[3 * v + 1];
    float dz = vb[3 * j + 2] - vb[3 * v + 2];
    float nrm = sqrtf(dx * dx + dy * dy + dz * dz);
    float m = fmaxf(nrm, 1e-12f);
    nd[tid * 3] = dx / m; nd[tid * 3 + 1] = dy / m; nd[tid * 3 + 2] = dz / m;
  }
  __syncthreads();
  {
    int e = tid;
    float s0 = sd[e], s1 = sd[128 + e], s2 = sd[256 + e];
    float me = 0.0f;
#pragma unroll
    for (int n = 0; n < NEI; ++n) {
      float th = nd[3 * n] * s0 + nd[3 * n + 1] * s1 + nd[3 * n + 2] * s2;
      th = fmaxf(th, 0.0f);
      me = fmaxf(me, th);
    }
    mcol[e] = me;
  }
  __syncthreads();
  if (tid < 32) {
    float o = mcol[tid] + mcol[32 + tid] + mcol[64 + tid] + mcol[96 + tid];
    o = fmaxf(o, 0.0f);
    fm[(size_t)row * 32 + tid] = o;
  }
}

// fp32 tiled GEMM 64x64x16 (guarded; used for layer1): C = A*W + bias
__global__ __launch_bounds__(256) void k_gemm_bias(const float* __restrict__ A,
                                                   const float* __restrict__ W,
                                                   const float* __restrict__ bias,
                                                   float* __restrict__ Cm,
                                                   int M, int N, int K) {
  __shared__ float As[16][68];
  __shared__ float Bs[16][68];
  int n0 = blockIdx.x * 64, m0 = blockIdx.y * 64;
  int tx = threadIdx.x & 15, ty = threadIdx.x >> 4;
  float acc[4][4] = {};
  for (int k0 = 0; k0 < K; k0 += 16) {
    for (int t = threadIdx.x; t < 1024; t += 256) {
      int mm = t >> 4, kk = t & 15;
      int m = m0 + mm;
      As[kk][mm] = (m < M) ? A[(size_t)m * K + (k0 + kk)] : 0.0f;
    }
    for (int t = threadIdx.x; t < 1024; t += 256) {
      int kk = t >> 6, nn = t & 63;
      int n = n0 + nn;
      Bs[kk][nn] = (n < N) ? san(W[(size_t)(k0 + kk) * N + n]) : 0.0f;
    }
    __syncthreads();
#pragma unroll
    for (int kk = 0; kk < 16; ++kk) {
      float4 av = *(const float4*)&As[kk][ty << 2];
      float4 bv = *(const float4*)&Bs[kk][tx << 2];
      float a[4] = {av.x, av.y, av.z, av.w};
      float bb[4] = {bv.x, bv.y, bv.z, bv.w};
#pragma unroll
      for (int i = 0; i < 4; ++i)
#pragma unroll
        for (int j = 0; j < 4; ++j) acc[i][j] += a[i] * bb[j];
    }
    __syncthreads();
  }
  for (int i = 0; i < 4; ++i)
    for (int j = 0; j < 4; ++j) {
      int m = m0 + (ty << 2) + i, n = n0 + (tx << 2) + j;
      if (m < M && n < N) Cm[(size_t)m * N + n] = acc[i][j] + san(bias[n]);
    }
}

// fp32 tiled GEMM 128x128x32, requires M%128==0, N%128==0, K%32==0.
__global__ __launch_bounds__(256) void k_gemm128(const float* __restrict__ A,
                                                 const float* __restrict__ W,
                                                 const float* __restrict__ bias,
                                                 float* __restrict__ Cm,
                                                 int M, int N, int K) {
  __shared__ float As[32][132];
  __shared__ float Bs[32][132];
  const int n0 = blockIdx.x * 128, m0 = blockIdx.y * 128;
  const int tx = threadIdx.x & 15, ty = threadIdx.x >> 4;
  const int bm = ty * 8;
  float acc[8][8] = {};
  float bias_lo[4], bias_hi[4];
#pragma unroll
  for (int j = 0; j < 4; ++j) {
    bias_lo[j] = san(bias[n0 + tx * 4 + j]);
    bias_hi[j] = san(bias[n0 + 64 + tx * 4 + j]);
  }
  for (int k0 = 0; k0 < K; k0 += 32) {
#pragma unroll
    for (int r = 0; r < 4; ++r) {
      int t = r * 256 + threadIdx.x;
      int mm = t >> 3, kk = (t & 7) * 4;
      float4 v = *(const float4*)&A[(size_t)(m0 + mm) * K + k0 + kk];
      As[kk + 0][mm] = v.x; As[kk + 1][mm] = v.y; As[kk + 2][mm] = v.z; As[kk + 3][mm] = v.w;
    }
#pragma unroll
    for (int r = 0; r < 4; ++r) {
      int t = r * 256 + threadIdx.x;
      int kk = t >> 5, nn = (t & 31) * 4;
      float4 v = *(const float4*)&W[(size_t)(k0 + kk) * N + n0 + nn];
      *(float4*)&Bs[kk][nn] = v;
    }
    __syncthreads();
#pragma unroll
    for (int kk = 0; kk < 32; ++kk) {
      float4 a0 = *(const float4*)&As[kk][bm];
      float4 a1 = *(const float4*)&As[kk][bm + 4];
      float4 b0 = *(const float4*)&Bs[kk][tx * 4];
      float4 b1 = *(const float4*)&Bs[kk][64 + tx * 4];
      float a[8] = {a0.x, a0.y, a0.z, a0.w, a1.x, a1.y, a1.z, a1.w};
      float bb[8] = {b0.x, b0.y, b0.z, b0.w, b1.x, b1.y, b1.z, b1.w};
#pragma unroll
      for (int i = 0; i < 8; ++i)
#pragma unroll
        for (int j = 0; j < 8; ++j) acc[i][j] += a[i] * bb[j];
    }
    __syncthreads();
  }
#pragma unroll
  for (int i = 0; i < 8; ++i) {
    int m = m0 + bm + i;
    float4 lo = {acc[i][0] + bias_lo[0], acc[i][1] + bias_lo[1],
                 acc[i][2] + bias_lo[2], acc[i][3] + bias_lo[3]};
    float4 hi = {acc[i][4] + bias_hi[0], acc[i][5] + bias_hi[1],
                 acc[i][6] + bias_hi[2], acc[i][7] + bias_hi[3]};
    *(float4*)&Cm[(size_t)m * N + n0 + tx * 4] = lo;
    *(float4*)&Cm[(size_t)m * N + n0 + 64 + tx * 4] = hi;
  }
}

// conv layer: out[c] = f[row][c] + sum_s max_n relu(nd_n . sd_e) * f[j_n][C+e]
__global__ __launch_bounds__(256) void k_conv_layer(const float* __restrict__ f,
                                                    const float* __restrict__ verts,
                                                    const int* __restrict__ nidx,
                                                    const float* __restrict__ sd,
                                                    float* __restrict__ outf,
                                                    int V, int C, int relu_out) {
  int row = blockIdx.x;
  int b = row / V, v = row % V;
  int E = 4 * C;
  extern __shared__ float sm[];
  float* mcol = sm;
  float* nd = sm + E;
  int* jr = (int*)(nd + 60);
  int tid = threadIdx.x;
  const float* vb = verts + (size_t)b * V * 3;
  if (tid < NEI) {
    int j = nidx[(size_t)row * NEI + tid];
    jr[tid] = j;
    float dx = vb[3 * j] - vb[3 * v];
    float dy = vb[3 * j + 1] - vb[3 * v + 1];
    float dz = vb[3 * j + 2] - vb[3 * v + 2];
    float nrm = sqrtf(dx * dx + dy * dy + dz * dz);
    float m = fmaxf(nrm, 1e-12f);
    nd[tid * 3] = dx / m; nd[tid * 3 + 1] = dy / m; nd[tid * 3 + 2] = dz / m;
  }
  __syncthreads();
  size_t fb = (size_t)b * V;
  int fivec = 5 * C;
  for (int e = tid; e < E; e += blockDim.x) {
    float s0 = sd[e], s1 = sd[E + e], s2 = sd[2 * E + e];
    float me = -INFINITY;
#pragma unroll
    for (int n = 0; n < NEI; ++n) {
      float th = nd[3 * n] * s0 + nd[3 * n + 1] * s1 + nd[3 * n + 2] * s2;
      th = fmaxf(th, 0.0f);
      float fv = f[(fb + jr[n]) * (size_t)fivec + C + e];
      me = fmaxf(me, th * fv);
    }
    mcol[e] = me;
  }
  __syncthreads();
  for (int c = tid; c < C; c += blockDim.x) {
    float o = f[(size_t)row * fivec + c] + mcol[c] + mcol[C + c] + mcol[2 * C + c] + mcol[3 * C + c];
    if (relu_out) o = fmaxf(o, 0.0f);
    outf[(size_t)row * C + c] = o;
  }
}

// transpose (B, V, C) -> (B, C, V), 32x32 LDS tiles, coalesced both sides
__global__ __launch_bounds__(256) void k_transpose_vc(const float* __restrict__ in,
                                                      float* __restrict__ out,
                                                      int V, int C) {
  __shared__ float tile[32][33];
  int b = blockIdx.z;
  int c0 = blockIdx.x * 32, v0 = blockIdx.y * 32;
  int tx = threadIdx.x & 31, ty4 = threadIdx.x >> 5;
#pragma unroll
  for (int j = 0; j < 4; ++j) {
    int v = v0 + ty4 * 4 + j;
    tile[ty4 * 4 + j][tx] = in[((size_t)b * V + v) * C + c0 + tx];
  }
  __syncthreads();
#pragma unroll
  for (int j = 0; j < 4; ++j) {
    int c = c0 + ty4 * 4 + j;
    out[((size_t)b * C + c) * V + v0 + tx] = tile[tx][ty4 * 4 + j];
  }
}

// fused pool (max over neighbors at selected rows) + pooled-vertex gather
__global__ void k_pool_sel(const float* __restrict__ fm, const int* __restrict__ nidx,
                           const int* __restrict__ sel, float* __restrict__ outp,
                           const float* __restrict__ vinA, float* __restrict__ voutA,
                           float* __restrict__ xs, float* __restrict__ ys,
                           float* __restrict__ zs, float* __restrict__ sqs,
                           int Vin, int Vout, int C) {
  int t = blockIdx.x * blockDim.x + threadIdx.x;
  if (t < 4 * Vout) {
    int p = t % Vout;
    int b = t / Vout;
    int src = b * Vin + sel[p];
    float x = vinA[3 * src], y = vinA[3 * src + 1], z = vinA[3 * src + 2];
    int dst = b * Vout + p;
    voutA[3 * dst] = x; voutA[3 * dst + 1] = y; voutA[3 * dst + 2] = z;
    xs[dst] = x; ys[dst] = y; zs[dst] = z;
    sqs[dst] = x * x + y * y + z * z;
  }
  int total = 4 * Vout * C;
  if (t >= total) return;
  int c = t % C;
  int p = (t / C) % Vout;
  int b = t / (C * Vout);
  int sv = sel[p];
  const int* ir = nidx + ((size_t)b * Vin + sv) * NEI;
  float m = -INFINITY;
#pragma unroll
  for (int n = 0; n < NEI; ++n)
    m = fmaxf(m, fm[((size_t)b * Vin + ir[n]) * C + c]);
  outp[((size_t)b * Vout + p) * C + c] = m;
}

// ===================== launch =====================
extern "C" void kernel_launch(void* const* d_in, const int* in_sizes, int n_in,
                              void* d_out, int out_size, void* d_ws, size_t ws_size,
                              hipStream_t stream) {
  (void)in_sizes; (void)n_in; (void)out_size; (void)ws_size;
  const int B = 4, V1 = 4096, V2 = 1024, V3 = 256;

  const float* vin   = (const float*)d_in[0];
  const float* dirs0 = (const float*)d_in[1];
  const float* W1 = (const float*)d_in[2];
  const float* b1 = (const float*)d_in[3];
  const float* D1 = (const float*)d_in[4];
  const float* W2 = (const float*)d_in[5];
  const float* b2 = (const float*)d_in[6];
  const float* D2 = (const float*)d_in[7];
  const float* W3 = (const float*)d_in[8];
  const float* b3 = (const float*)d_in[9];
  const float* D3 = (const float*)d_in[10];
  const float* W4 = (const float*)d_in[11];
  const float* b4 = (const float*)d_in[12];
  const float* D4 = (const float*)d_in[13];
  float* out = (float*)d_out;

  char* ws = (char*)d_ws;
  size_t off = 0;
  auto alloc = [&](size_t bytes) -> char* {
    char* p = ws + off;
    off = (off + bytes + 255) & ~(size_t)255;
    return p;
  };
  int* sel1 = (int*)alloc((size_t)V2 * 4);
  int* sel2 = (int*)alloc((size_t)V3 * 4);
  float* verts1 = (float*)alloc((size_t)B * V1 * 3 * 4);
  float* verts2 = (float*)alloc((size_t)B * V2 * 3 * 4);
  float* verts3 = (float*)alloc((size_t)B * V3 * 3 * 4);
  float* xs1 = (float*)alloc((size_t)B * V1 * 4);
  float* ys1 = (float*)alloc((size_t)B * V1 * 4);
  float* zs1 = (float*)alloc((size_t)B * V1 * 4);
  float* sq1 = (float*)alloc((size_t)B * V1 * 4);
  float* xs2 = (float*)alloc((size_t)B * V2 * 4);
  float* ys2 = (float*)alloc((size_t)B * V2 * 4);
  float* zs2 = (float*)alloc((size_t)B * V2 * 4);
  float* sq2 = (float*)alloc((size_t)B * V2 * 4);
  float* xs3 = (float*)alloc((size_t)B * V3 * 4);
  float* ys3 = (float*)alloc((size_t)B * V3 * 4);
  float* zs3 = (float*)alloc((size_t)B * V3 * 4);
  float* sq3 = (float*)alloc((size_t)B * V3 * 4);
  int* idx1 = (int*)alloc((size_t)B * V1 * NEI * 4);
  int* idx2 = (int*)alloc((size_t)B * V2 * NEI * 4);
  int* idx3 = (int*)alloc((size_t)B * V3 * NEI * 4);
  float* sd0 = (float*)alloc(3 * 128 * 4);
  float* sd1 = (float*)alloc(3 * 256 * 4);
  float* sd2 = (float*)alloc(3 * 512 * 4);
  float* sd3 = (float*)alloc(3 * 1024 * 4);
  float* sd4 = (float*)alloc(3 * 4096 * 4);
  float* bufA = (float*)alloc((size_t)B * V1 * 32 * 4);
  float* bufB = (float*)alloc((size_t)B * V1 * 64 * 4);
  float* bufC = (float*)alloc((size_t)B * V2 * 64 * 4);
  float* fbuf = (float*)alloc((size_t)B * V1 * 320 * 4);
  float* fm0 = bufA, *fm2 = bufA;
  float* fm1 = bufB, *fm3 = bufB;
  float* fm1p = bufC, *fm3p = bufC;
  float* conv4out = bufB;

  static int perm1[4096];
  static int perm2[1024];
  static int selh[1280];
  jax_permutation(42u, 4096, 2, perm1);
  jax_permutation(43u, 1024, 1, perm2);
  memcpy(selh, perm1, 1024 * sizeof(int));
  memcpy(selh + 1024, perm2, 256 * sizeof(int));
  hipMemcpyAsync(sel1, selh, 1024 * sizeof(int), hipMemcpyHostToDevice, stream);
  hipMemcpyAsync(sel2, selh + 1024, 256 * sizeof(int), hipMemcpyHostToDevice, stream);

  // fused sanitize + dirs normalize
  k_setup<<<88, 256, 0, stream>>>(vin, verts1, xs1, ys1, zs1, sq1, B * V1,
                                  dirs0, D1, D2, D3, D4, sd0, sd1, sd2, sd3, sd4);
  // knn level 1 (VCAND = 64), 2 queries/wave, 8 queries/block
  k_knn10<64><<<B * V1 / 8, 256, 0, stream>>>(xs1, ys1, zs1, sq1, idx1, V1);
  k_conv_surface<<<B * V1, 128, 0, stream>>>(verts1, idx1, sd0, fm0, V1);
  // layer1 (N=320 not /128 -> 64-tile)
  k_gemm_bias<<<dim3(5, 256), 256, 0, stream>>>(fm0, W1, b1, fbuf, B * V1, 320, 32);
  k_conv_layer<<<B * V1, 256, (4 * 64 + 80) * 4, stream>>>(fbuf, verts1, idx1, sd1, fm1, V1, 64, 1);
  // pool1 (fused pool + vertex gather)
  {
    int total = B * V2 * 64;
    k_pool_sel<<<(total + 255) / 256, 256, 0, stream>>>(fm1, idx1, sel1, fm1p,
                                                        verts1, verts2, xs2, ys2, zs2, sq2,
                                                        V1, V2, 64);
  }
  // knn level 2 (VCAND = 16)
  k_knn10<16><<<B * V2 / 8, 256, 0, stream>>>(xs2, ys2, zs2, sq2, idx2, V2);
  // layer2: 4096x640x64
  k_gemm128<<<dim3(640 / 128, 4096 / 128), 256, 0, stream>>>(fm1p, W2, b2, fbuf, B * V2, 640, 64);
  k_conv_layer<<<B * V2, 256, (4 * 128 + 80) * 4, stream>>>(fbuf, verts2, idx2, sd2, fm2, V2, 128, 1);
  // layer3: 4096x1280x128
  k_gemm128<<<dim3(1280 / 128, 4096 / 128), 256, 0, stream>>>(fm2, W3, b3, fbuf, B * V2, 1280, 128);
  k_conv_layer<<<B * V2, 256, (4 * 256 + 80) * 4, stream>>>(fbuf, verts2, idx2, sd3, fm3, V2, 256, 1);
  // pool2 (fused)
  {
    int total = B * V3 * 256;
    k_pool_sel<<<(total + 255) / 256, 256, 0, stream>>>(fm3, idx2, sel2, fm3p,
                                                        verts2, verts3, xs3, ys3, zs3, sq3,
                                                        V2, V3, 256);
  }
  // knn level 3 (VCAND = 4)
  k_knn10<4><<<B * V3 / 8, 256, 0, stream>>>(xs3, ys3, zs3, sq3, idx3, V3);
  // layer4: 1024x5120x256, conv C=1024 row-major, then coalesced transpose
  k_gemm128<<<dim3(5120 / 128, 1024 / 128), 256, 0, stream>>>(fm3p, W4, b4, fbuf, B * V3, 5120, 256);
  k_conv_layer<<<B * V3, 256, (4 * 1024 + 80) * 4, stream>>>(fbuf, verts3, idx3, sd4, conv4out, V3, 1024, 0);
  k_transpose_vc<<<dim3(1024 / 32, 256 / 32, B), 256, 0, stream>>>(conv4out, out, V3, 1024);
}

// Round 14
// 449.914 us; speedup vs baseline: 1.9672x; 1.9072x over previous
//
#include <hip/hip_runtime.h>
#include <vector>
#include <algorithm>
#include <cstdint>
#include <cstring>
#include <cmath>

// ===================== host-side JAX threefry replication =====================
static inline uint32_t tf_rotl(uint32_t x, int r) { return (x << r) | (x >> (32 - r)); }

static void tf2x32(uint32_t k0, uint32_t k1, uint32_t x0, uint32_t x1,
                   uint32_t* o0, uint32_t* o1) {
  uint32_t ks2 = k0 ^ k1 ^ 0x1BD11BDAu;
  uint32_t v0 = x0 + k0, v1 = x1 + k1;
  static const int R0[4] = {13, 15, 26, 6}, R1[4] = {17, 29, 16, 24};
#define RND4(R) do { for (int i_ = 0; i_ < 4; ++i_) { v0 += v1; v1 = tf_rotl(v1, R[i_]); v1 ^= v0; } } while (0)
  RND4(R0); v0 += k1;  v1 += ks2 + 1u;
  RND4(R1); v0 += ks2; v1 += k0 + 2u;
  RND4(R0); v0 += k0;  v1 += k1 + 3u;
  RND4(R1); v0 += k1;  v1 += ks2 + 4u;
  RND4(R0); v0 += ks2; v1 += k0 + 5u;
#undef RND4
  *o0 = v0; *o1 = v1;
}

static void jax_permutation(uint32_t seed, int n, int rounds, int* x) {
  uint32_t k0 = 0u, k1 = seed;
  for (int i = 0; i < n; ++i) x[i] = i;
  std::vector<uint32_t> bits(n);
  std::vector<int> ord(n), xn(n);
  for (int r = 0; r < rounds; ++r) {
    uint32_t nk0, nk1, sk0, sk1;
    tf2x32(k0, k1, 0u, 0u, &nk0, &nk1);
    tf2x32(k0, k1, 0u, 1u, &sk0, &sk1);
    for (int i = 0; i < n; ++i) {
      uint32_t h, l;
      tf2x32(sk0, sk1, 0u, (uint32_t)i, &h, &l);
      bits[i] = h ^ l;
    }
    for (int i = 0; i < n; ++i) ord[i] = i;
    std::stable_sort(ord.begin(), ord.end(),
                     [&](int a, int b) { return bits[a] < bits[b]; });
    for (int i = 0; i < n; ++i) xn[i] = x[ord[i]];
    memcpy(x, xn.data(), (size_t)n * sizeof(int));
    k0 = nk0; k1 = nk1;
  }
}

// ===================== device kernels =====================
#define NEI 20

__device__ __forceinline__ float san(float v) {
  v = (v != v) ? 0.0f : v;
  return fmaxf(-1e4f, fminf(v, 1e4f));
}

// fused setup: blocks 0..63 sanitize vertices -> AoS + SoA + sq;
// blocks 64..87 normalize the 5 direction matrices.
__global__ void k_setup(const float* __restrict__ vin, float* __restrict__ outA,
                        float* __restrict__ xs, float* __restrict__ ys,
                        float* __restrict__ zs, float* __restrict__ sqs, int nverts,
                        const float* __restrict__ d0, const float* __restrict__ d1,
                        const float* __restrict__ d2, const float* __restrict__ d3,
                        const float* __restrict__ d4,
                        float* __restrict__ s0, float* __restrict__ s1,
                        float* __restrict__ s2, float* __restrict__ s3,
                        float* __restrict__ s4) {
  int blk = blockIdx.x;
  if (blk < 64) {
    int i = blk * 256 + threadIdx.x;
    if (i >= nverts) return;
    float x = san(vin[3 * i]), y = san(vin[3 * i + 1]), z = san(vin[3 * i + 2]);
    outA[3 * i] = x; outA[3 * i + 1] = y; outA[3 * i + 2] = z;
    xs[i] = x; ys[i] = y; zs[i] = z;
    sqs[i] = x * x + y * y + z * z;
    return;
  }
  int t = (blk - 64) * 256 + threadIdx.x;
  const float* d; float* s; int E, e;
  if (t < 128)       { d = d0; s = s0; E = 128;  e = t; }
  else if (t < 384)  { d = d1; s = s1; E = 256;  e = t - 128; }
  else if (t < 896)  { d = d2; s = s2; E = 512;  e = t - 384; }
  else if (t < 1920) { d = d3; s = s3; E = 1024; e = t - 896; }
  else if (t < 6016) { d = d4; s = s4; E = 4096; e = t - 1920; }
  else return;
  float a = san(d[e]);
  float b = san(d[E + e]);
  float c = san(d[2 * E + e]);
  float nrm = sqrtf(a * a + b * b + c * c);
  float m = fmaxf(nrm, 1e-12f);
  s[e] = a / m; s[E + e] = b / m; s[2 * E + e] = c / m;
}

// total-order map for fp32 bits: monotone u32 for any float (handles negatives)
__device__ __forceinline__ unsigned fmap(float f) {
  unsigned u = __float_as_uint(f);
  return u ^ ((u & 0x80000000u) ? 0xFFFFFFFFu : 0x80000000u);
}

// --- 64-lane u32 min, broadcast to all lanes: 6 DPP (VALU pipe) + 1 shfl ---
__device__ __forceinline__ unsigned dpp_min_bcast1(unsigned a) {
  unsigned t;
  t = (unsigned)__builtin_amdgcn_update_dpp((int)a, (int)a, 0xB1, 0xF, 0xF, true);
  a = t < a ? t : a;
  t = (unsigned)__builtin_amdgcn_update_dpp((int)a, (int)a, 0x4E, 0xF, 0xF, true);
  a = t < a ? t : a;
  t = (unsigned)__builtin_amdgcn_update_dpp((int)a, (int)a, 0x141, 0xF, 0xF, true);
  a = t < a ? t : a;
  t = (unsigned)__builtin_amdgcn_update_dpp((int)a, (int)a, 0x140, 0xF, 0xF, true);
  a = t < a ? t : a;
  t = (unsigned)__builtin_amdgcn_update_dpp((int)a, (int)a, 0x142, 0xA, 0xF, false);
  a = t < a ? t : a;
  t = (unsigned)__builtin_amdgcn_update_dpp((int)a, (int)a, 0x143, 0xC, 0xF, false);
  a = t < a ? t : a;
  return (unsigned)__shfl((int)a, 63);
}

__device__ __forceinline__ void dpp_min_bcast2(unsigned& a, unsigned& b) {
  unsigned t0, t1;
#define STEP_DPP(ctrl, rm, bc)                                                           \
  t0 = (unsigned)__builtin_amdgcn_update_dpp((int)a, (int)a, ctrl, rm, 0xF, bc);         \
  t1 = (unsigned)__builtin_amdgcn_update_dpp((int)b, (int)b, ctrl, rm, 0xF, bc);         \
  a = t0 < a ? t0 : a; b = t1 < b ? t1 : b;
  STEP_DPP(0xB1, 0xF, true)
  STEP_DPP(0x4E, 0xF, true)
  STEP_DPP(0x141, 0xF, true)
  STEP_DPP(0x140, 0xF, true)
  STEP_DPP(0x142, 0xA, false)
  STEP_DPP(0x143, 0xC, false)
#undef STEP_DPP
  a = (unsigned)__shfl((int)a, 63);
  b = (unsigned)__shfl((int)b, 63);
}

// KNN v8 (restored from R10 — proven 100 µs, zero spill): two queries per wave;
// lane-local sorted top-3 u64 queues of (fmap(dist)<<32 | j); per round a u32
// DPP min over the mapped dist word of the heads; ballot tie-break by index.
// Dual-queue variants (R11/R12) spilled to scratch regardless of launch bounds
// (1 GB WRITE_SIZE, 4.7x regression) — do not revisit.
template <int VCAND>
__global__ __launch_bounds__(256, 8) void k_knn8(const float* __restrict__ xs,
                                                 const float* __restrict__ ys,
                                                 const float* __restrict__ zs,
                                                 const float* __restrict__ sqs,
                                                 int* __restrict__ nidx, int V) {
  const int wid = threadIdx.x >> 6;
  const int lane = threadIdx.x & 63;
  const int row0 = blockIdx.x * 8 + wid * 2;
  const int b = row0 / V;
  const int base = b * V;
  const int i0 = row0 % V;

  float xi[2], yi[2], zi[2], sqi[2];
#pragma unroll
  for (int t = 0; t < 2; ++t) {
    xi[t] = xs[base + i0 + t]; yi[t] = ys[base + i0 + t]; zi[t] = zs[base + i0 + t];
    sqi[t] = sqs[base + i0 + t];
  }

  unsigned long long q0[2] = {~0ULL, ~0ULL}, q1[2] = {~0ULL, ~0ULL}, q2[2] = {~0ULL, ~0ULL};
#pragma unroll 4
  for (int c = 0; c < VCAND; ++c) {
    int j = c * 64 + lane;
    float xj = xs[base + j], yj = ys[base + j], zj = zs[base + j];
    float sqj = sqs[base + j];
#pragma unroll
    for (int t = 0; t < 2; ++t) {
      float dot = xi[t] * xj + yi[t] * yj + zi[t] * zj;
      float dd = (sqi[t] + sqj) - 2.0f * dot;
      unsigned long long k = (((unsigned long long)fmap(dd)) << 32) | (unsigned)j;
      if (k < q2[t]) {
        if (k < q1[t]) {
          q2[t] = q1[t];
          if (k < q0[t]) { q1[t] = q0[t]; q0[t] = k; } else { q1[t] = k; }
        } else {
          q2[t] = k;
        }
      }
    }
  }

  for (int r = 0; r < 21; ++r) {
    unsigned h0 = (unsigned)(q0[0] >> 32);
    unsigned h1 = (unsigned)(q0[1] >> 32);
    unsigned m0 = h0, m1 = h1;
    dpp_min_bcast2(m0, m1);
    unsigned long long mk0 = __ballot(h0 == m0);
    unsigned long long mk1 = __ballot(h1 == m1);
    bool win0, win1;
    if (__popcll(mk0) > 1) {  // rare: dist-bit tie across lanes -> index min
      unsigned jj = (h0 == m0) ? (unsigned)q0[0] : 0xFFFFFFFFu;
      unsigned jm = dpp_min_bcast1(jj);
      win0 = (h0 == m0) && ((unsigned)q0[0] == jm);
    } else {
      win0 = (h0 == m0);
    }
    if (__popcll(mk1) > 1) {
      unsigned jj = (h1 == m1) ? (unsigned)q0[1] : 0xFFFFFFFFu;
      unsigned jm = dpp_min_bcast1(jj);
      win1 = (h1 == m1) && ((unsigned)q0[1] == jm);
    } else {
      win1 = (h1 == m1);
    }
    if (win0) {
      if (r > 0) nidx[(size_t)row0 * NEI + (r - 1)] = (int)(unsigned)q0[0];
      unsigned long long bound = q0[0];
      q0[0] = q1[0]; q1[0] = q2[0]; q2[0] = ~0ULL;
      if (q0[0] == ~0ULL) {
        unsigned long long nm = ~0ULL;
        for (int c = 0; c < VCAND; ++c) {
          int j = c * 64 + lane;
          float xj = xs[base + j], yj = ys[base + j], zj = zs[base + j];
          float sqj = sqs[base + j];
          float dot = xi[0] * xj + yi[0] * yj + zi[0] * zj;
          float dd = (sqi[0] + sqj) - 2.0f * dot;
          unsigned long long k = (((unsigned long long)fmap(dd)) << 32) | (unsigned)j;
          if (k > bound && k < nm) nm = k;
        }
        q0[0] = nm;
      }
    }
    if (win1) {
      if (r > 0) nidx[(size_t)(row0 + 1) * NEI + (r - 1)] = (int)(unsigned)q0[1];
      unsigned long long bound = q0[1];
      q0[1] = q1[1]; q1[1] = q2[1]; q2[1] = ~0ULL;
      if (q0[1] == ~0ULL) {
        unsigned long long nm = ~0ULL;
        for (int c = 0; c < VCAND; ++c) {
          int j = c * 64 + lane;
          float xj = xs[base + j], yj = ys[base + j], zj = zs[base + j];
          float sqj = sqs[base + j];
          float dot = xi[1] * xj + yi[1] * yj + zi[1] * zj;
          float dd = (sqi[1] + sqj) - 2.0f * dot;
          unsigned long long k = (((unsigned long long)fmap(dd)) << 32) | (unsigned)j;
          if (k > bound && k < nm) nm = k;
        }
        q0[1] = nm;
      }
    }
  }
}

// conv_surface: C=32, E=128. One block (128 thr) per (b,v).
__global__ __launch_bounds__(128) void k_conv_surface(const float* __restrict__ verts,
                                                      const int* __restrict__ nidx,
                                                      const float* __restrict__ sd,
                                                      float* __restrict__ fm, int V) {
  int row = blockIdx.x;
  int b = row / V, v = row % V;
  const float* vb = verts + (size_t)b * V * 3;
  __shared__ float nd[60];
  __shared__ float mcol[128];
  int tid = threadIdx.x;
  if (tid < NEI) {
    int j = nidx[(size_t)row * NEI + tid];
    float dx = vb[3 * j] - vb[3 * v];
    float dy = vb[3 * j + 1] - vb[3 * v + 1];
    float dz = vb[3 * j + 2] - vb[3 * v + 2];
    float nrm = sqrtf(dx * dx + dy * dy + dz * dz);
    float m = fmaxf(nrm, 1e-12f);
    nd[tid * 3] = dx / m; nd[tid * 3 + 1] = dy / m; nd[tid * 3 + 2] = dz / m;
  }
  __syncthreads();
  {
    int e = tid;
    float s0 = sd[e], s1 = sd[128 + e], s2 = sd[256 + e];
    float me = 0.0f;
#pragma unroll
    for (int n = 0; n < NEI; ++n) {
      float th = nd[3 * n] * s0 + nd[3 * n + 1] * s1 + nd[3 * n + 2] * s2;
      th = fmaxf(th, 0.0f);
      me = fmaxf(me, th);
    }
    mcol[e] = me;
  }
  __syncthreads();
  if (tid < 32) {
    float o = mcol[tid] + mcol[32 + tid] + mcol[64 + tid] + mcol[96 + tid];
    o = fmaxf(o, 0.0f);
    fm[(size_t)row * 32 + tid] = o;
  }
}

// fp32 tiled GEMM 64x64x16 (guarded; used for layer1): C = A*W + bias
__global__ __launch_bounds__(256) void k_gemm_bias(const float* __restrict__ A,
                                                   const float* __restrict__ W,
                                                   const float* __restrict__ bias,
                                                   float* __restrict__ Cm,
                                                   int M, int N, int K) {
  __shared__ float As[16][68];
  __shared__ float Bs[16][68];
  int n0 = blockIdx.x * 64, m0 = blockIdx.y * 64;
  int tx = threadIdx.x & 15, ty = threadIdx.x >> 4;
  float acc[4][4] = {};
  for (int k0 = 0; k0 < K; k0 += 16) {
    for (int t = threadIdx.x; t < 1024; t += 256) {
      int mm = t >> 4, kk = t & 15;
      int m = m0 + mm;
      As[kk][mm] = (m < M) ? A[(size_t)m * K + (k0 + kk)] : 0.0f;
    }
    for (int t = threadIdx.x; t < 1024; t += 256) {
      int kk = t >> 6, nn = t & 63;
      int n = n0 + nn;
      Bs[kk][nn] = (n < N) ? san(W[(size_t)(k0 + kk) * N + n]) : 0.0f;
    }
    __syncthreads();
#pragma unroll
    for (int kk = 0; kk < 16; ++kk) {
      float4 av = *(const float4*)&As[kk][ty << 2];
      float4 bv = *(const float4*)&Bs[kk][tx << 2];
      float a[4] = {av.x, av.y, av.z, av.w};
      float bb[4] = {bv.x, bv.y, bv.z, bv.w};
#pragma unroll
      for (int i = 0; i < 4; ++i)
#pragma unroll
        for (int j = 0; j < 4; ++j) acc[i][j] += a[i] * bb[j];
    }
    __syncthreads();
  }
  for (int i = 0; i < 4; ++i)
    for (int j = 0; j < 4; ++j) {
      int m = m0 + (ty << 2) + i, n = n0 + (tx << 2) + j;
      if (m < M && n < N) Cm[(size_t)m * N + n] = acc[i][j] + san(bias[n]);
    }
}

// fp32 tiled GEMM 128x128x32, requires M%128==0, N%128==0, K%32==0.
__global__ __launch_bounds__(256) void k_gemm128(const float* __restrict__ A,
                                                 const float* __restrict__ W,
                                                 const float* __restrict__ bias,
                                                 float* __restrict__ Cm,
                                                 int M, int N, int K) {
  __shared__ float As[32][132];
  __shared__ float Bs[32][132];
  const int n0 = blockIdx.x * 128, m0 = blockIdx.y * 128;
  const int tx = threadIdx.x & 15, ty = threadIdx.x >> 4;
  const int bm = ty * 8;
  float acc[8][8] = {};
  float bias_lo[4], bias_hi[4];
#pragma unroll
  for (int j = 0; j < 4; ++j) {
    bias_lo[j] = san(bias[n0 + tx * 4 + j]);
    bias_hi[j] = san(bias[n0 + 64 + tx * 4 + j]);
  }
  for (int k0 = 0; k0 < K; k0 += 32) {
#pragma unroll
    for (int r = 0; r < 4; ++r) {
      int t = r * 256 + threadIdx.x;
      int mm = t >> 3, kk = (t & 7) * 4;
      float4 v = *(const float4*)&A[(size_t)(m0 + mm) * K + k0 + kk];
      As[kk + 0][mm] = v.x; As[kk + 1][mm] = v.y; As[kk + 2][mm] = v.z; As[kk + 3][mm] = v.w;
    }
#pragma unroll
    for (int r = 0; r < 4; ++r) {
      int t = r * 256 + threadIdx.x;
      int kk = t >> 5, nn = (t & 31) * 4;
      float4 v = *(const float4*)&W[(size_t)(k0 + kk) * N + n0 + nn];
      *(float4*)&Bs[kk][nn] = v;
    }
    __syncthreads();
#pragma unroll
    for (int kk = 0; kk < 32; ++kk) {
      float4 a0 = *(const float4*)&As[kk][bm];
      float4 a1 = *(const float4*)&As[kk][bm + 4];
      float4 b0 = *(const float4*)&Bs[kk][tx * 4];
      float4 b1 = *(const float4*)&Bs[kk][64 + tx * 4];
      float a[8] = {a0.x, a0.y, a0.z, a0.w, a1.x, a1.y, a1.z, a1.w};
      float bb[8] = {b0.x, b0.y, b0.z, b0.w, b1.x, b1.y, b1.z, b1.w};
#pragma unroll
      for (int i = 0; i < 8; ++i)
#pragma unroll
        for (int j = 0; j < 8; ++j) acc[i][j] += a[i] * bb[j];
    }
    __syncthreads();
  }
#pragma unroll
  for (int i = 0; i < 8; ++i) {
    int m = m0 + bm + i;
    float4 lo = {acc[i][0] + bias_lo[0], acc[i][1] + bias_lo[1],
                 acc[i][2] + bias_lo[2], acc[i][3] + bias_lo[3]};
    float4 hi = {acc[i][4] + bias_hi[0], acc[i][5] + bias_hi[1],
                 acc[i][6] + bias_hi[2], acc[i][7] + bias_hi[3]};
    *(float4*)&Cm[(size_t)m * N + n0 + tx * 4] = lo;
    *(float4*)&Cm[(size_t)m * N + n0 + 64 + tx * 4] = hi;
  }
}

// conv layer: out[c] = f[row][c] + sum_s max_n relu(nd_n . sd_e) * f[j_n][C+e]
__global__ __launch_bounds__(256) void k_conv_layer(const float* __restrict__ f,
                                                    const float* __restrict__ verts,
                                                    const int* __restrict__ nidx,
                                                    const float* __restrict__ sd,
                                                    float* __restrict__ outf,
                                                    int V, int C, int relu_out) {
  int row = blockIdx.x;
  int b = row / V, v = row % V;
  int E = 4 * C;
  extern __shared__ float sm[];
  float* mcol = sm;
  float* nd = sm + E;
  int* jr = (int*)(nd + 60);
  int tid = threadIdx.x;
  const float* vb = verts + (size_t)b * V * 3;
  if (tid < NEI) {
    int j = nidx[(size_t)row * NEI + tid];
    jr[tid] = j;
    float dx = vb[3 * j] - vb[3 * v];
    float dy = vb[3 * j + 1] - vb[3 * v + 1];
    float dz = vb[3 * j + 2] - vb[3 * v + 2];
    float nrm = sqrtf(dx * dx + dy * dy + dz * dz);
    float m = fmaxf(nrm, 1e-12f);
    nd[tid * 3] = dx / m; nd[tid * 3 + 1] = dy / m; nd[tid * 3 + 2] = dz / m;
  }
  __syncthreads();
  size_t fb = (size_t)b * V;
  int fivec = 5 * C;
  for (int e = tid; e < E; e += blockDim.x) {
    float s0 = sd[e], s1 = sd[E + e], s2 = sd[2 * E + e];
    float me = -INFINITY;
#pragma unroll
    for (int n = 0; n < NEI; ++n) {
      float th = nd[3 * n] * s0 + nd[3 * n + 1] * s1 + nd[3 * n + 2] * s2;
      th = fmaxf(th, 0.0f);
      float fv = f[(fb + jr[n]) * (size_t)fivec + C + e];
      me = fmaxf(me, th * fv);
    }
    mcol[e] = me;
  }
  __syncthreads();
  for (int c = tid; c < C; c += blockDim.x) {
    float o = f[(size_t)row * fivec + c] + mcol[c] + mcol[C + c] + mcol[2 * C + c] + mcol[3 * C + c];
    if (relu_out) o = fmaxf(o, 0.0f);
    outf[(size_t)row * C + c] = o;
  }
}

// transpose (B, V, C) -> (B, C, V), 32x32 LDS tiles, coalesced both sides
__global__ __launch_bounds__(256) void k_transpose_vc(const float* __restrict__ in,
                                                      float* __restrict__ out,
                                                      int V, int C) {
  __shared__ float tile[32][33];
  int b = blockIdx.z;
  int c0 = blockIdx.x * 32, v0 = blockIdx.y * 32;
  int tx = threadIdx.x & 31, ty4 = threadIdx.x >> 5;
#pragma unroll
  for (int j = 0; j < 4; ++j) {
    int v = v0 + ty4 * 4 + j;
    tile[ty4 * 4 + j][tx] = in[((size_t)b * V + v) * C + c0 + tx];
  }
  __syncthreads();
#pragma unroll
  for (int j = 0; j < 4; ++j) {
    int c = c0 + ty4 * 4 + j;
    out[((size_t)b * C + c) * V + v0 + tx] = tile[tx][ty4 * 4 + j];
  }
}

// fused pool (max over neighbors at selected rows) + pooled-vertex gather
__global__ void k_pool_sel(const float* __restrict__ fm, const int* __restrict__ nidx,
                           const int* __restrict__ sel, float* __restrict__ outp,
                           const float* __restrict__ vinA, float* __restrict__ voutA,
                           float* __restrict__ xs, float* __restrict__ ys,
                           float* __restrict__ zs, float* __restrict__ sqs,
                           int Vin, int Vout, int C) {
  int t = blockIdx.x * blockDim.x + threadIdx.x;
  if (t < 4 * Vout) {
    int p = t % Vout;
    int b = t / Vout;
    int src = b * Vin + sel[p];
    float x = vinA[3 * src], y = vinA[3 * src + 1], z = vinA[3 * src + 2];
    int dst = b * Vout + p;
    voutA[3 * dst] = x; voutA[3 * dst + 1] = y; voutA[3 * dst + 2] = z;
    xs[dst] = x; ys[dst] = y; zs[dst] = z;
    sqs[dst] = x * x + y * y + z * z;
  }
  int total = 4 * Vout * C;
  if (t >= total) return;
  int c = t % C;
  int p = (t / C) % Vout;
  int b = t / (C * Vout);
  int sv = sel[p];
  const int* ir = nidx + ((size_t)b * Vin + sv) * NEI;
  float m = -INFINITY;
#pragma unroll
  for (int n = 0; n < NEI; ++n)
    m = fmaxf(m, fm[((size_t)b * Vin + ir[n]) * C + c]);
  outp[((size_t)b * Vout + p) * C + c] = m;
}

// ===================== launch =====================
extern "C" void kernel_launch(void* const* d_in, const int* in_sizes, int n_in,
                              void* d_out, int out_size, void* d_ws, size_t ws_size,
                              hipStream_t stream) {
  (void)in_sizes; (void)n_in; (void)out_size; (void)ws_size;
  const int B = 4, V1 = 4096, V2 = 1024, V3 = 256;

  const float* vin   = (const float*)d_in[0];
  const float* dirs0 = (const float*)d_in[1];
  const float* W1 = (const float*)d_in[2];
  const float* b1 = (const float*)d_in[3];
  const float* D1 = (const float*)d_in[4];
  const float* W2 = (const float*)d_in[5];
  const float* b2 = (const float*)d_in[6];
  const float* D2 = (const float*)d_in[7];
  const float* W3 = (const float*)d_in[8];
  const float* b3 = (const float*)d_in[9];
  const float* D3 = (const float*)d_in[10];
  const float* W4 = (const float*)d_in[11];
  const float* b4 = (const float*)d_in[12];
  const float* D4 = (const float*)d_in[13];
  float* out = (float*)d_out;

  char* ws = (char*)d_ws;
  size_t off = 0;
  auto alloc = [&](size_t bytes) -> char* {
    char* p = ws + off;
    off = (off + bytes + 255) & ~(size_t)255;
    return p;
  };
  int* sel1 = (int*)alloc((size_t)V2 * 4);
  int* sel2 = (int*)alloc((size_t)V3 * 4);
  float* verts1 = (float*)alloc((size_t)B * V1 * 3 * 4);
  float* verts2 = (float*)alloc((size_t)B * V2 * 3 * 4);
  float* verts3 = (float*)alloc((size_t)B * V3 * 3 * 4);
  float* xs1 = (float*)alloc((size_t)B * V1 * 4);
  float* ys1 = (float*)alloc((size_t)B * V1 * 4);
  float* zs1 = (float*)alloc((size_t)B * V1 * 4);
  float* sq1 = (float*)alloc((size_t)B * V1 * 4);
  float* xs2 = (float*)alloc((size_t)B * V2 * 4);
  float* ys2 = (float*)alloc((size_t)B * V2 * 4);
  float* zs2 = (float*)alloc((size_t)B * V2 * 4);
  float* sq2 = (float*)alloc((size_t)B * V2 * 4);
  float* xs3 = (float*)alloc((size_t)B * V3 * 4);
  float* ys3 = (float*)alloc((size_t)B * V3 * 4);
  float* zs3 = (float*)alloc((size_t)B * V3 * 4);
  float* sq3 = (float*)alloc((size_t)B * V3 * 4);
  int* idx1 = (int*)alloc((size_t)B * V1 * NEI * 4);
  int* idx2 = (int*)alloc((size_t)B * V2 * NEI * 4);
  int* idx3 = (int*)alloc((size_t)B * V3 * NEI * 4);
  float* sd0 = (float*)alloc(3 * 128 * 4);
  float* sd1 = (float*)alloc(3 * 256 * 4);
  float* sd2 = (float*)alloc(3 * 512 * 4);
  float* sd3 = (float*)alloc(3 * 1024 * 4);
  float* sd4 = (float*)alloc(3 * 4096 * 4);
  float* bufA = (float*)alloc((size_t)B * V1 * 32 * 4);
  float* bufB = (float*)alloc((size_t)B * V1 * 64 * 4);
  float* bufC = (float*)alloc((size_t)B * V2 * 64 * 4);
  float* fbuf = (float*)alloc((size_t)B * V1 * 320 * 4);
  float* fm0 = bufA, *fm2 = bufA;
  float* fm1 = bufB, *fm3 = bufB;
  float* fm1p = bufC, *fm3p = bufC;
  float* conv4out = bufB;

  static int perm1[4096];
  static int perm2[1024];
  static int selh[1280];
  jax_permutation(42u, 4096, 2, perm1);
  jax_permutation(43u, 1024, 1, perm2);
  memcpy(selh, perm1, 1024 * sizeof(int));
  memcpy(selh + 1024, perm2, 256 * sizeof(int));
  hipMemcpyAsync(sel1, selh, 1024 * sizeof(int), hipMemcpyHostToDevice, stream);
  hipMemcpyAsync(sel2, selh + 1024, 256 * sizeof(int), hipMemcpyHostToDevice, stream);

  // fused sanitize + dirs normalize
  k_setup<<<88, 256, 0, stream>>>(vin, verts1, xs1, ys1, zs1, sq1, B * V1,
                                  dirs0, D1, D2, D3, D4, sd0, sd1, sd2, sd3, sd4);
  // knn level 1 (VCAND = 64), 2 queries/wave, 8 queries/block
  k_knn8<64><<<B * V1 / 8, 256, 0, stream>>>(xs1, ys1, zs1, sq1, idx1, V1);
  k_conv_surface<<<B * V1, 128, 0, stream>>>(verts1, idx1, sd0, fm0, V1);
  // layer1 (N=320 not /128 -> 64-tile)
  k_gemm_bias<<<dim3(5, 256), 256, 0, stream>>>(fm0, W1, b1, fbuf, B * V1, 320, 32);
  k_conv_layer<<<B * V1, 256, (4 * 64 + 80) * 4, stream>>>(fbuf, verts1, idx1, sd1, fm1, V1, 64, 1);
  // pool1 (fused pool + vertex gather)
  {
    int total = B * V2 * 64;
    k_pool_sel<<<(total + 255) / 256, 256, 0, stream>>>(fm1, idx1, sel1, fm1p,
                                                        verts1, verts2, xs2, ys2, zs2, sq2,
                                                        V1, V2, 64);
  }
  // knn level 2 (VCAND = 16)
  k_knn8<16><<<B * V2 / 8, 256, 0, stream>>>(xs2, ys2, zs2, sq2, idx2, V2);
  // layer2: 4096x640x64
  k_gemm128<<<dim3(640 / 128, 4096 / 128), 256, 0, stream>>>(fm1p, W2, b2, fbuf, B * V2, 640, 64);
  k_conv_layer<<<B * V2, 256, (4 * 128 + 80) * 4, stream>>>(fbuf, verts2, idx2, sd2, fm2, V2, 128, 1);
  // layer3: 4096x1280x128
  k_gemm128<<<dim3(1280 / 128, 4096 / 128), 256, 0, stream>>>(fm2, W3, b3, fbuf, B * V2, 1280, 128);
  k_conv_layer<<<B * V2, 256, (4 * 256 + 80) * 4, stream>>>(fbuf, verts2, idx2, sd3, fm3, V2, 256, 1);
  // pool2 (fused)
  {
    int total = B * V3 * 256;
    k_pool_sel<<<(total + 255) / 256, 256, 0, stream>>>(fm3, idx2, sel2, fm3p,
                                                        verts2, verts3, xs3, ys3, zs3, sq3,
                                                        V2, V3, 256);
  }
  // knn level 3 (VCAND = 4)
  k_knn8<4><<<B * V3 / 8, 256, 0, stream>>>(xs3, ys3, zs3, sq3, idx3, V3);
  // layer4: 1024x5120x256, conv C=1024 row-major, then coalesced transpose
  k_gemm128<<<dim3(5120 / 128, 1024 / 128), 256, 0, stream>>>(fm3p, W4, b4, fbuf, B * V3, 5120, 256);
  k_conv_layer<<<B * V3, 256, (4 * 1024 + 80) * 4, stream>>>(fbuf, verts3, idx3, sd4, conv4out, V3, 1024, 0);
  k_transpose_vc<<<dim3(1024 / 32, 256 / 32, B), 256, 0, stream>>>(conv4out, out, V3, 1024);
}